// Round 4
// baseline (260.013 us; speedup 1.0000x reference)
//
#include <hip/hip_runtime.h>

typedef unsigned short u16;
typedef __attribute__((ext_vector_type(8))) short short8;   // 8 bf16 = 4 VGPRs
typedef __attribute__((ext_vector_type(4))) float f32x4;

#define D 2048
#define EPS 1e-5f

__device__ __forceinline__ u16 f2bf(float f) {
  unsigned u = __float_as_uint(f);
  u += 0x7fffu + ((u >> 16) & 1u);   // round-to-nearest-even
  return (u16)(u >> 16);
}

__device__ __forceinline__ void async16(const void* g, void* l) {
  __builtin_amdgcn_global_load_lds(
      (const __attribute__((address_space(1))) void*)g,
      (__attribute__((address_space(3))) void*)l, 16, 0, 0);
}

// ============ kernel 1: fused row-LN (out=x prefill) + weight transpose/cvt ============
__global__ __launch_bounds__(256) void prep(const float* __restrict__ x,
                                            const float* __restrict__ Wq,
                                            const float* __restrict__ Wk,
                                            const float* __restrict__ Wv,
                                            const float* __restrict__ Wo,
                                            u16* __restrict__ xn,
                                            float* __restrict__ out,
                                            u16* __restrict__ WqT, u16* __restrict__ WkT,
                                            u16* __restrict__ WvT, u16* __restrict__ WoT) {
  int bid = blockIdx.x;
  int t = threadIdx.x;
  if (bid < 2048) {
    const float* xr = x + (size_t)bid * D;
    float4 v[2];
    float s = 0.f, sq = 0.f;
#pragma unroll
    for (int i = 0; i < 2; i++) {
      v[i] = *(const float4*)(xr + i * 1024 + t * 4);
      s += v[i].x + v[i].y + v[i].z + v[i].w;
      sq += v[i].x * v[i].x + v[i].y * v[i].y + v[i].z * v[i].z + v[i].w * v[i].w;
    }
#pragma unroll
    for (int m = 32; m >= 1; m >>= 1) { s += __shfl_xor(s, m); sq += __shfl_xor(sq, m); }
    __shared__ float ps[4], pq[4];
    int w = t >> 6, lane = t & 63;
    if (lane == 0) { ps[w] = s; pq[w] = sq; }
    __syncthreads();
    s = ps[0] + ps[1] + ps[2] + ps[3];
    sq = pq[0] + pq[1] + pq[2] + pq[3];
    float mean = s * (1.f / D);
    float var = sq * (1.f / D) - mean * mean;
    float rs = rsqrtf(var + EPS);
    float* outr = out + (size_t)bid * D;
    u16* xnr = xn + (size_t)bid * D;
#pragma unroll
    for (int i = 0; i < 2; i++) {
      *(float4*)(outr + i * 1024 + t * 4) = v[i];      // residual base
      ushort4 o;
      o.x = f2bf((v[i].x - mean) * rs);
      o.y = f2bf((v[i].y - mean) * rs);
      o.z = f2bf((v[i].z - mean) * rs);
      o.w = f2bf((v[i].w - mean) * rs);
      *(ushort4*)(xnr + i * 1024 + t * 4) = o;
    }
  } else {
    int tb = bid - 2048;
    int wsel = tb >> 10;
    int tt = tb & 1023;
    const float* src; u16* dst;
    switch (wsel) {
      case 0: src = Wq; dst = WqT; break;
      case 1: src = Wk; dst = WkT; break;
      case 2: src = Wv; dst = WvT; break;
      default: src = Wo; dst = WoT; break;
    }
    int i0 = (tt >> 5) * 64, j0 = (tt & 31) * 64;
    __shared__ u16 tile[64 * 66];
#pragma unroll
    for (int r = 0; r < 4; r++) {
      int idx = r * 256 + t;
      int row = idx >> 4, c4 = idx & 15;
      float4 v = *(const float4*)(src + (size_t)(i0 + row) * D + j0 + c4 * 4);
      tile[row * 66 + c4 * 4 + 0] = f2bf(v.x);
      tile[row * 66 + c4 * 4 + 1] = f2bf(v.y);
      tile[row * 66 + c4 * 4 + 2] = f2bf(v.z);
      tile[row * 66 + c4 * 4 + 3] = f2bf(v.w);
    }
    __syncthreads();
#pragma unroll
    for (int r = 0; r < 4; r++) {
      int idx = r * 256 + t;
      int row = idx >> 4, c4 = idx & 15;
      ushort4 o;
      o.x = tile[(c4 * 4 + 0) * 66 + row];
      o.y = tile[(c4 * 4 + 1) * 66 + row];
      o.z = tile[(c4 * 4 + 2) * 66 + row];
      o.w = tile[(c4 * 4 + 3) * 66 + row];
      *(ushort4*)(dst + (size_t)(j0 + row) * D + i0 + c4 * 4) = o;   // dst[n][k]=src[k][n]
    }
  }
}

// ============ single-buffered 128x128-tile bf16 MFMA GEMM body (m97 structure) ============
__device__ __forceinline__ void gemm_tile(const u16* __restrict__ A,
                                          const u16* __restrict__ Bt,
                                          bool permB, int m0, int n0,
                                          int kbeg, int kend,
                                          u16* As, u16* Bs, f32x4 acc[4][4]) {
  int tid = threadIdx.x, wid = tid >> 6, lane = tid & 63;
  int q4 = lane >> 4, m16 = lane & 15;
  int wm = wid >> 1, wn = wid & 1;
  for (int kb = kbeg; kb < kend; kb += 64) {
#pragma unroll
    for (int p = 0; p < 4; p++) {
      int idx = p * 256 + tid;         // chunk id 0..1023
      int r = idx >> 3, sl = idx & 7;
      int gc = sl ^ (r & 7);           // XOR-swizzled column chunk
      async16(A + (size_t)(m0 + r) * D + kb + gc * 8, As + (size_t)(p * 256 + wid * 64) * 8);
      int rb = n0 + r;
      int gr = permB ? ((rb & 127) * 16 + (rb >> 7)) : rb;  // token perm for V
      async16(Bt + (size_t)gr * D + kb + gc * 8, Bs + (size_t)(p * 256 + wid * 64) * 8);
    }
    __syncthreads();
#pragma unroll
    for (int ks = 0; ks < 2; ks++) {
      short8 af[4], bf[4];
      int c = ks * 4 + q4;
#pragma unroll
      for (int i = 0; i < 4; i++) {
        int ra = wm * 64 + i * 16 + m16;
        af[i] = *(const short8*)(As + ra * 64 + (c ^ (ra & 7)) * 8);
        int rb = wn * 64 + i * 16 + m16;
        bf[i] = *(const short8*)(Bs + rb * 64 + (c ^ (rb & 7)) * 8);
      }
#pragma unroll
      for (int i = 0; i < 4; i++)
#pragma unroll
        for (int j = 0; j < 4; j++)
          acc[i][j] = __builtin_amdgcn_mfma_f32_16x16x32_bf16(af[i], bf[j], acc[i][j], 0, 0, 0);
    }
    __syncthreads();
  }
}

// ============ kernel 2: mega-GEMM with fused LN / layout epilogues ============
// bid [0,256):   K = xn @ Wk   -> head-LN -> K3[h][b][key][dhl]
// bid [256,512): V = (Wv^T @ xn^T) token-permuted -> V3[h][b][dhl][key]
// bid [512,544): Q = xn[0:256] @ Wq -> head-LN -> Q3[h][tok][dhl]
__global__ __launch_bounds__(256) void gemm_mega(const u16* __restrict__ xn,
                                                 const u16* __restrict__ WkT,
                                                 const u16* __restrict__ WqT,
                                                 const u16* __restrict__ WvT,
                                                 u16* __restrict__ K3,
                                                 u16* __restrict__ Q3,
                                                 u16* __restrict__ V3) {
  __shared__ u16 smem[2 * 128 * 64];   // 32 KB
  u16* As = smem;
  u16* Bs = smem + 8192;
  int bid = blockIdx.x;
  int sel = (bid < 256) ? 0 : (bid < 512) ? 2 : 1;
  int z = (sel == 1) ? bid - 512 : (bid & 255);
  int m0 = (z >> 4) * 128, n0 = (z & 15) * 128;
  const u16* A = (sel == 2) ? WvT : xn;
  const u16* Bt = (sel == 0) ? WkT : (sel == 1) ? WqT : xn;
  f32x4 acc[4][4];
#pragma unroll
  for (int i = 0; i < 4; i++)
#pragma unroll
    for (int j = 0; j < 4; j++)
#pragma unroll
      for (int r = 0; r < 4; r++) acc[i][j][r] = 0.f;
  gemm_tile(A, Bt, sel == 2, m0, n0, 0, D, As, Bs, acc);

  int tid = threadIdx.x, wid = tid >> 6, lane = tid & 63;
  int q4 = lane >> 4, m16 = lane & 15;
  int wm = wid >> 1, wn = wid & 1;
  if (sel == 2) {
    int h = m0 >> 7, b = n0 >> 7;
#pragma unroll
    for (int i = 0; i < 4; i++)
#pragma unroll
      for (int j = 0; j < 4; j++)
#pragma unroll
        for (int r = 0; r < 4; r++) {
          int dhl = wm * 64 + i * 16 + q4 * 4 + r;     // C/D: row=(lane>>4)*4+reg
          int key = wn * 64 + j * 16 + m16;            //      col=lane&15
          V3[((size_t)(h * 16 + b) * 128 + dhl) * 128 + key] = f2bf(acc[i][j][r]);
        }
  } else {
    // fused head-LN: rows = tokens, 128 cols = this head's dims (tile-aligned)
    float* redS = (float*)smem;        // [128][2]
    float* redQ = redS + 256;          // [128][2]
    float ps[4][4], pq[4][4];
#pragma unroll
    for (int i = 0; i < 4; i++)
#pragma unroll
      for (int r = 0; r < 4; r++) {
        float s = 0.f, q = 0.f;
#pragma unroll
        for (int j = 0; j < 4; j++) { float a = acc[i][j][r]; s += a; q += a * a; }
        ps[i][r] = s; pq[i][r] = q;
      }
#pragma unroll
    for (int msk = 1; msk < 16; msk <<= 1)
#pragma unroll
      for (int i = 0; i < 4; i++)
#pragma unroll
        for (int r = 0; r < 4; r++) {
          ps[i][r] += __shfl_xor(ps[i][r], msk);
          pq[i][r] += __shfl_xor(pq[i][r], msk);
        }
    __syncthreads();                   // smem free for reduction scratch
    if (m16 == 0) {
#pragma unroll
      for (int i = 0; i < 4; i++)
#pragma unroll
        for (int r = 0; r < 4; r++) {
          int row = wm * 64 + i * 16 + q4 * 4 + r;
          redS[row * 2 + wn] = ps[i][r];
          redQ[row * 2 + wn] = pq[i][r];
        }
    }
    __syncthreads();
    int h = n0 >> 7;
#pragma unroll
    for (int i = 0; i < 4; i++)
#pragma unroll
      for (int r = 0; r < 4; r++) {
        int row = wm * 64 + i * 16 + q4 * 4 + r;
        float S = redS[row * 2] + redS[row * 2 + 1];
        float Qs = redQ[row * 2] + redQ[row * 2 + 1];
        float mean = S * (1.f / 128.f);
        float var = Qs * (1.f / 128.f) - mean * mean;
        float rstd = rsqrtf(var + EPS);
        int tok = m0 + row;
#pragma unroll
        for (int j = 0; j < 4; j++) {
          int dhl = wn * 64 + j * 16 + m16;
          u16 val = f2bf((acc[i][j][r] - mean) * rstd);
          if (sel == 0)
            K3[(((size_t)(h * 16 + (tok & 15))) * 128 + (tok >> 4)) * 128 + dhl] = val;
          else
            Q3[((size_t)h * 256 + tok) * 128 + dhl] = val;
        }
      }
  }
}

// ============ kernel 3: attention, 256 blocks=(b,h), dense tiled reads ============
__global__ __launch_bounds__(128) void attn(const u16* __restrict__ Q3,
                                            const u16* __restrict__ K3,
                                            const u16* __restrict__ V3,
                                            u16* __restrict__ Ob) {
  int bh = blockIdx.x;
  int b = bh & 15, h = bh >> 4;
  int tid = threadIdx.x, w = tid >> 6, lane = tid & 63;
  int q4 = lane >> 4, m16 = lane & 15;
  __shared__ float redmx[2][16];
  __shared__ float redsm[2][16];
  __shared__ float invd[16];
  __shared__ u16 P[16][136];
  const float scale = 0.08838834764831845f;   // 1/sqrt(128)
  const u16* Ktile = K3 + (size_t)(h * 16 + b) * 128 * 128;
  const u16* Vtile = V3 + (size_t)(h * 16 + b) * 128 * 128;

  short8 af[4];
#pragma unroll
  for (int dc = 0; dc < 4; dc++)
    af[dc] = *(const short8*)(Q3 + ((size_t)h * 256 + b * 16 + m16) * 128 + dc * 32 + q4 * 8);
  f32x4 s[4];
#pragma unroll
  for (int kt = 0; kt < 4; kt++)
#pragma unroll
    for (int r = 0; r < 4; r++) s[kt][r] = 0.f;
#pragma unroll
  for (int kt = 0; kt < 4; kt++) {
    int key = w * 64 + kt * 16 + m16;
#pragma unroll
    for (int dc = 0; dc < 4; dc++) {
      short8 bf = *(const short8*)(Ktile + (size_t)key * 128 + dc * 32 + q4 * 8);
      s[kt] = __builtin_amdgcn_mfma_f32_16x16x32_bf16(af[dc], bf, s[kt], 0, 0, 0);
    }
  }
  float mx[4];
#pragma unroll
  for (int r = 0; r < 4; r++) {
    mx[r] = fmaxf(fmaxf(s[0][r], s[1][r]), fmaxf(s[2][r], s[3][r]));
#pragma unroll
    for (int msk = 1; msk < 16; msk <<= 1) mx[r] = fmaxf(mx[r], __shfl_xor(mx[r], msk));
  }
  if (m16 == 0) {
#pragma unroll
    for (int r = 0; r < 4; r++) redmx[w][q4 * 4 + r] = mx[r];
  }
  __syncthreads();
#pragma unroll
  for (int r = 0; r < 4; r++) {
    float M = fmaxf(redmx[0][q4 * 4 + r], redmx[1][q4 * 4 + r]);
    float acc = 0.f;
#pragma unroll
    for (int kt = 0; kt < 4; kt++) {
      float e = __expf((s[kt][r] - M) * scale);
      s[kt][r] = e;
      acc += e;
    }
#pragma unroll
    for (int msk = 1; msk < 16; msk <<= 1) acc += __shfl_xor(acc, msk);
    if (m16 == 0) redsm[w][q4 * 4 + r] = acc;
  }
#pragma unroll
  for (int kt = 0; kt < 4; kt++)
#pragma unroll
    for (int r = 0; r < 4; r++)
      P[q4 * 4 + r][w * 64 + kt * 16 + m16] = f2bf(s[kt][r]);
  __syncthreads();
  if (tid < 16) invd[tid] = 1.0f / (redsm[0][tid] + redsm[1][tid]);
  __syncthreads();

  short8 pf[4];
#pragma unroll
  for (int kc = 0; kc < 4; kc++)
    pf[kc] = *(const short8*)(&P[m16][kc * 32 + q4 * 8]);
  f32x4 o[4];
#pragma unroll
  for (int dt = 0; dt < 4; dt++)
#pragma unroll
    for (int r = 0; r < 4; r++) o[dt][r] = 0.f;
#pragma unroll
  for (int dt = 0; dt < 4; dt++) {
    int dhl = (w * 4 + dt) * 16 + m16;
#pragma unroll
    for (int kc = 0; kc < 4; kc++) {
      short8 vf = *(const short8*)(Vtile + (size_t)dhl * 128 + kc * 32 + q4 * 8);
      o[dt] = __builtin_amdgcn_mfma_f32_16x16x32_bf16(pf[kc], vf, o[dt], 0, 0, 0);
    }
  }
#pragma unroll
  for (int dt = 0; dt < 4; dt++)
#pragma unroll
    for (int r = 0; r < 4; r++) {
      int row = q4 * 4 + r;
      float val = o[dt][r] * invd[row];
      Ob[(size_t)(b * 16 + row) * D + h * 128 + (w * 4 + dt) * 16 + m16] = f2bf(val);
    }
}

// ============ kernel 4: Wpart[z] = O @ Wo[z-slice]  (split-K=8, plain stores) ============
__global__ __launch_bounds__(256) void gemm_wo(const u16* __restrict__ Ob,
                                               const u16* __restrict__ WoT,
                                               float* __restrict__ Wpart) {
  __shared__ u16 smem[2 * 128 * 64];   // 32 KB
  u16* As = smem;
  u16* Bs = smem + 8192;
  int m0 = blockIdx.x * 128, n0 = blockIdx.y * 128;
  int z = blockIdx.z;
  int k0 = z * 256;
  f32x4 acc[4][4];
#pragma unroll
  for (int i = 0; i < 4; i++)
#pragma unroll
    for (int j = 0; j < 4; j++)
#pragma unroll
      for (int r = 0; r < 4; r++) acc[i][j][r] = 0.f;
  gemm_tile(Ob, WoT, false, m0, n0, k0, k0 + 256, As, Bs, acc);
  float* C = Wpart + (size_t)z * 256 * D;
  int tid = threadIdx.x, wid = tid >> 6, lane = tid & 63;
  int q4 = lane >> 4, m16 = lane & 15;
  int wm = wid >> 1, wn = wid & 1;
#pragma unroll
  for (int i = 0; i < 4; i++)
#pragma unroll
    for (int j = 0; j < 4; j++)
#pragma unroll
      for (int r = 0; r < 4; r++) {
        int row = m0 + wm * 64 + i * 16 + q4 * 4 + r;
        int col = n0 + wn * 64 + j * 16 + m16;
        C[(size_t)row * D + col] = acc[i][j][r];
      }
}

// ============ kernel 5: out[0:256] += sum_z Wpart[z]  (vectorized, no atomics) ============
__global__ __launch_bounds__(256) void reduce_wo(const float* __restrict__ Wpart,
                                                 float* __restrict__ out) {
  int i = (blockIdx.x * 256 + threadIdx.x) * 4;   // 512 blocks cover 256*2048 elems
  float4 s = *(const float4*)(out + i);           // residual base (out = x)
#pragma unroll
  for (int z = 0; z < 8; z++) {
    float4 p = *(const float4*)(Wpart + (size_t)z * 256 * D + i);
    s.x += p.x; s.y += p.y; s.z += p.z; s.w += p.w;
  }
  *(float4*)(out + i) = s;
}

extern "C" void kernel_launch(void* const* d_in, const int* in_sizes, int n_in,
                              void* d_out, int out_size, void* d_ws, size_t ws_size,
                              hipStream_t stream) {
  const float* x  = (const float*)d_in[0];
  const float* Wq = (const float*)d_in[1];
  const float* Wk = (const float*)d_in[2];
  const float* Wv = (const float*)d_in[3];
  const float* Wo = (const float*)d_in[4];
  float* out = (float*)d_out;
  char* w = (char*)d_ws;
  const size_t MB = 1u << 20;
  u16*   xn    = (u16*)(w);              // 0-8
  u16*   WqT   = (u16*)(w + 8 * MB);     // 8-16
  u16*   WkT   = (u16*)(w + 16 * MB);    // 16-24
  u16*   WvT   = (u16*)(w + 24 * MB);    // 24-32
  u16*   WoT   = (u16*)(w + 32 * MB);    // 32-40
  u16*   K3    = (u16*)(w + 40 * MB);    // 40-48
  u16*   V3    = (u16*)(w + 48 * MB);    // 48-56
  u16*   Q3    = (u16*)(w + 56 * MB);    // 56-57
  u16*   Obf   = (u16*)(w + 57 * MB);    // 57-58
  float* Wpart = (float*)(w + 58 * MB);  // 58-74  (8 x 2MB fp32 partials)

  prep<<<dim3(6144), dim3(256), 0, stream>>>(x, Wq, Wk, Wv, Wo, xn, out, WqT, WkT, WvT, WoT);
  gemm_mega<<<dim3(544), dim3(256), 0, stream>>>(xn, WkT, WqT, WvT, K3, Q3, V3);
  attn<<<dim3(256), dim3(128), 0, stream>>>(Q3, K3, V3, Obf);
  gemm_wo<<<dim3(2, 16, 8), dim3(256), 0, stream>>>(Obf, WoT, Wpart);
  reduce_wo<<<dim3(512), dim3(256), 0, stream>>>(Wpart, out);
}

// Round 5
// 195.954 us; speedup vs baseline: 1.3269x; 1.3269x over previous
//
#include <hip/hip_runtime.h>

typedef unsigned short u16;
typedef __attribute__((ext_vector_type(8))) short short8;   // 8 bf16 = 4 VGPRs
typedef __attribute__((ext_vector_type(4))) float f32x4;

#define D 2048
#define EPS 1e-5f

__device__ __forceinline__ u16 f2bf(float f) {
  unsigned u = __float_as_uint(f);
  u += 0x7fffu + ((u >> 16) & 1u);   // round-to-nearest-even
  return (u16)(u >> 16);
}

__device__ __forceinline__ void async16(const void* g, void* l) {
  __builtin_amdgcn_global_load_lds(
      (const __attribute__((address_space(1))) void*)g,
      (__attribute__((address_space(3))) void*)l, 16, 0, 0);
}

// ============ kernel 1: fused row-LN (out=x prefill) + weight transpose/cvt ============
__global__ __launch_bounds__(256) void prep(const float* __restrict__ x,
                                            const float* __restrict__ Wq,
                                            const float* __restrict__ Wk,
                                            const float* __restrict__ Wv,
                                            const float* __restrict__ Wo,
                                            u16* __restrict__ xn,
                                            float* __restrict__ out,
                                            u16* __restrict__ WqT, u16* __restrict__ WkT,
                                            u16* __restrict__ WvT, u16* __restrict__ WoT) {
  int bid = blockIdx.x;
  int t = threadIdx.x;
  if (bid < 2048) {
    const float* xr = x + (size_t)bid * D;
    float4 v[2];
    float s = 0.f, sq = 0.f;
#pragma unroll
    for (int i = 0; i < 2; i++) {
      v[i] = *(const float4*)(xr + i * 1024 + t * 4);
      s += v[i].x + v[i].y + v[i].z + v[i].w;
      sq += v[i].x * v[i].x + v[i].y * v[i].y + v[i].z * v[i].z + v[i].w * v[i].w;
    }
#pragma unroll
    for (int m = 32; m >= 1; m >>= 1) { s += __shfl_xor(s, m); sq += __shfl_xor(sq, m); }
    __shared__ float ps[4], pq[4];
    int w = t >> 6, lane = t & 63;
    if (lane == 0) { ps[w] = s; pq[w] = sq; }
    __syncthreads();
    s = ps[0] + ps[1] + ps[2] + ps[3];
    sq = pq[0] + pq[1] + pq[2] + pq[3];
    float mean = s * (1.f / D);
    float var = sq * (1.f / D) - mean * mean;
    float rs = rsqrtf(var + EPS);
    float* outr = out + (size_t)bid * D;
    u16* xnr = xn + (size_t)bid * D;
#pragma unroll
    for (int i = 0; i < 2; i++) {
      *(float4*)(outr + i * 1024 + t * 4) = v[i];      // residual base
      ushort4 o;
      o.x = f2bf((v[i].x - mean) * rs);
      o.y = f2bf((v[i].y - mean) * rs);
      o.z = f2bf((v[i].z - mean) * rs);
      o.w = f2bf((v[i].w - mean) * rs);
      *(ushort4*)(xnr + i * 1024 + t * 4) = o;
    }
  } else {
    int tb = bid - 2048;
    int wsel = tb >> 10;
    int tt = tb & 1023;
    const float* src; u16* dst;
    switch (wsel) {
      case 0: src = Wq; dst = WqT; break;
      case 1: src = Wk; dst = WkT; break;
      case 2: src = Wv; dst = WvT; break;
      default: src = Wo; dst = WoT; break;
    }
    int i0 = (tt >> 5) * 64, j0 = (tt & 31) * 64;
    __shared__ u16 tile[64 * 66];
#pragma unroll
    for (int r = 0; r < 4; r++) {
      int idx = r * 256 + t;
      int row = idx >> 4, c4 = idx & 15;
      float4 v = *(const float4*)(src + (size_t)(i0 + row) * D + j0 + c4 * 4);
      tile[row * 66 + c4 * 4 + 0] = f2bf(v.x);
      tile[row * 66 + c4 * 4 + 1] = f2bf(v.y);
      tile[row * 66 + c4 * 4 + 2] = f2bf(v.z);
      tile[row * 66 + c4 * 4 + 3] = f2bf(v.w);
    }
    __syncthreads();
#pragma unroll
    for (int r = 0; r < 4; r++) {
      int idx = r * 256 + t;
      int row = idx >> 4, c4 = idx & 15;
      ushort4 o;
      o.x = tile[(c4 * 4 + 0) * 66 + row];
      o.y = tile[(c4 * 4 + 1) * 66 + row];
      o.z = tile[(c4 * 4 + 2) * 66 + row];
      o.w = tile[(c4 * 4 + 3) * 66 + row];
      *(ushort4*)(dst + (size_t)(j0 + row) * D + i0 + c4 * 4) = o;   // dst[n][k]=src[k][n]
    }
  }
}

// ============ single-buffered 128x128-tile bf16 MFMA GEMM body (m97 structure) ============
__device__ __forceinline__ void gemm_tile(const u16* __restrict__ A,
                                          const u16* __restrict__ Bt,
                                          bool permB, int m0, int n0,
                                          int kbeg, int kend,
                                          u16* As, u16* Bs, f32x4 acc[4][4]) {
  int tid = threadIdx.x, wid = tid >> 6, lane = tid & 63;
  int q4 = lane >> 4, m16 = lane & 15;
  int wm = wid >> 1, wn = wid & 1;
  for (int kb = kbeg; kb < kend; kb += 64) {
#pragma unroll
    for (int p = 0; p < 4; p++) {
      int idx = p * 256 + tid;         // chunk id 0..1023
      int r = idx >> 3, sl = idx & 7;
      int gc = sl ^ (r & 7);           // XOR-swizzled column chunk
      async16(A + (size_t)(m0 + r) * D + kb + gc * 8, As + (size_t)(p * 256 + wid * 64) * 8);
      int rb = n0 + r;
      int gr = permB ? ((rb & 127) * 16 + (rb >> 7)) : rb;  // token perm for V
      async16(Bt + (size_t)gr * D + kb + gc * 8, Bs + (size_t)(p * 256 + wid * 64) * 8);
    }
    __syncthreads();
#pragma unroll
    for (int ks = 0; ks < 2; ks++) {
      short8 af[4], bf[4];
      int c = ks * 4 + q4;
#pragma unroll
      for (int i = 0; i < 4; i++) {
        int ra = wm * 64 + i * 16 + m16;
        af[i] = *(const short8*)(As + ra * 64 + (c ^ (ra & 7)) * 8);
        int rb = wn * 64 + i * 16 + m16;
        bf[i] = *(const short8*)(Bs + rb * 64 + (c ^ (rb & 7)) * 8);
      }
#pragma unroll
      for (int i = 0; i < 4; i++)
#pragma unroll
        for (int j = 0; j < 4; j++)
          acc[i][j] = __builtin_amdgcn_mfma_f32_16x16x32_bf16(af[i], bf[j], acc[i][j], 0, 0, 0);
    }
    __syncthreads();
  }
}

// ============ kernel 2: mega-GEMM with fused LN / layout epilogues ============
// bid [0,256):   K = xn @ Wk   -> head-LN -> K3[h][b][key][dhl]
// bid [256,512): V = (Wv^T @ xn^T) token-permuted -> V3[h][b][dhl][key]
// bid [512,544): Q = xn[0:256] @ Wq -> head-LN -> Q3[h][tok][dhl]
// __launch_bounds__(256,3): cap regs so VGPR+AGPR fits 3 waves/SIMD (r4: 140+64 -> 2 waves, 120us)
__global__ __launch_bounds__(256, 3) void gemm_mega(const u16* __restrict__ xn,
                                                    const u16* __restrict__ WkT,
                                                    const u16* __restrict__ WqT,
                                                    const u16* __restrict__ WvT,
                                                    u16* __restrict__ K3,
                                                    u16* __restrict__ Q3,
                                                    u16* __restrict__ V3) {
  __shared__ u16 smem[2 * 128 * 64];   // 32 KB
  u16* As = smem;
  u16* Bs = smem + 8192;
  int bid = blockIdx.x;
  int sel = (bid < 256) ? 0 : (bid < 512) ? 2 : 1;
  int z = (sel == 1) ? bid - 512 : (bid & 255);
  int m0 = (z >> 4) * 128, n0 = (z & 15) * 128;
  const u16* A = (sel == 2) ? WvT : xn;
  const u16* Bt = (sel == 0) ? WkT : (sel == 1) ? WqT : xn;
  f32x4 acc[4][4];
#pragma unroll
  for (int i = 0; i < 4; i++)
#pragma unroll
    for (int j = 0; j < 4; j++)
#pragma unroll
      for (int r = 0; r < 4; r++) acc[i][j][r] = 0.f;
  gemm_tile(A, Bt, sel == 2, m0, n0, 0, D, As, Bs, acc);

  int tid = threadIdx.x, wid = tid >> 6, lane = tid & 63;
  int q4 = lane >> 4, m16 = lane & 15;
  int wm = wid >> 1, wn = wid & 1;
  if (sel == 2) {
    int h = m0 >> 7, b = n0 >> 7;
#pragma unroll
    for (int i = 0; i < 4; i++)
#pragma unroll
      for (int j = 0; j < 4; j++)
#pragma unroll
        for (int r = 0; r < 4; r++) {
          int dhl = wm * 64 + i * 16 + q4 * 4 + r;     // C/D: row=(lane>>4)*4+reg
          int key = wn * 64 + j * 16 + m16;            //      col=lane&15
          V3[((size_t)(h * 16 + b) * 128 + dhl) * 128 + key] = f2bf(acc[i][j][r]);
        }
  } else {
    // fused head-LN: rows = tokens, 128 cols = this head's dims (tile-aligned)
    float* redS = (float*)smem;        // [128][2]
    float* redQ = redS + 256;          // [128][2]
    __syncthreads();                   // smem free for reduction scratch
#pragma unroll
    for (int i = 0; i < 4; i++) {      // i-by-i to limit register liveness
      float ps[4], pq[4];
#pragma unroll
      for (int r = 0; r < 4; r++) {
        float s = 0.f, q = 0.f;
#pragma unroll
        for (int j = 0; j < 4; j++) { float a = acc[i][j][r]; s += a; q += a * a; }
#pragma unroll
        for (int msk = 1; msk < 16; msk <<= 1) {
          s += __shfl_xor(s, msk);
          q += __shfl_xor(q, msk);
        }
        ps[r] = s; pq[r] = q;
      }
      if (m16 == 0) {
#pragma unroll
        for (int r = 0; r < 4; r++) {
          int row = wm * 64 + i * 16 + q4 * 4 + r;
          redS[row * 2 + wn] = ps[r];
          redQ[row * 2 + wn] = pq[r];
        }
      }
    }
    __syncthreads();
    int h = n0 >> 7;
#pragma unroll
    for (int i = 0; i < 4; i++)
#pragma unroll
      for (int r = 0; r < 4; r++) {
        int row = wm * 64 + i * 16 + q4 * 4 + r;
        float S = redS[row * 2] + redS[row * 2 + 1];
        float Qs = redQ[row * 2] + redQ[row * 2 + 1];
        float mean = S * (1.f / 128.f);
        float var = Qs * (1.f / 128.f) - mean * mean;
        float rstd = rsqrtf(var + EPS);
        int tok = m0 + row;
#pragma unroll
        for (int j = 0; j < 4; j++) {
          int dhl = wn * 64 + j * 16 + m16;
          u16 val = f2bf((acc[i][j][r] - mean) * rstd);
          if (sel == 0)
            K3[(((size_t)(h * 16 + (tok & 15))) * 128 + (tok >> 4)) * 128 + dhl] = val;
          else
            Q3[((size_t)h * 256 + tok) * 128 + dhl] = val;
        }
      }
  }
}

// ============ kernel 3: attention, 256 blocks=(b,h), dense tiled reads ============
__global__ __launch_bounds__(128) void attn(const u16* __restrict__ Q3,
                                            const u16* __restrict__ K3,
                                            const u16* __restrict__ V3,
                                            u16* __restrict__ Ob) {
  int bh = blockIdx.x;
  int b = bh & 15, h = bh >> 4;
  int tid = threadIdx.x, w = tid >> 6, lane = tid & 63;
  int q4 = lane >> 4, m16 = lane & 15;
  __shared__ float redmx[2][16];
  __shared__ float redsm[2][16];
  __shared__ float invd[16];
  __shared__ u16 P[16][136];
  const float scale = 0.08838834764831845f;   // 1/sqrt(128)
  const u16* Ktile = K3 + (size_t)(h * 16 + b) * 128 * 128;
  const u16* Vtile = V3 + (size_t)(h * 16 + b) * 128 * 128;

  short8 af[4];
#pragma unroll
  for (int dc = 0; dc < 4; dc++)
    af[dc] = *(const short8*)(Q3 + ((size_t)h * 256 + b * 16 + m16) * 128 + dc * 32 + q4 * 8);
  f32x4 s[4];
#pragma unroll
  for (int kt = 0; kt < 4; kt++)
#pragma unroll
    for (int r = 0; r < 4; r++) s[kt][r] = 0.f;
#pragma unroll
  for (int kt = 0; kt < 4; kt++) {
    int key = w * 64 + kt * 16 + m16;
#pragma unroll
    for (int dc = 0; dc < 4; dc++) {
      short8 bf = *(const short8*)(Ktile + (size_t)key * 128 + dc * 32 + q4 * 8);
      s[kt] = __builtin_amdgcn_mfma_f32_16x16x32_bf16(af[dc], bf, s[kt], 0, 0, 0);
    }
  }
  float mx[4];
#pragma unroll
  for (int r = 0; r < 4; r++) {
    mx[r] = fmaxf(fmaxf(s[0][r], s[1][r]), fmaxf(s[2][r], s[3][r]));
#pragma unroll
    for (int msk = 1; msk < 16; msk <<= 1) mx[r] = fmaxf(mx[r], __shfl_xor(mx[r], msk));
  }
  if (m16 == 0) {
#pragma unroll
    for (int r = 0; r < 4; r++) redmx[w][q4 * 4 + r] = mx[r];
  }
  __syncthreads();
#pragma unroll
  for (int r = 0; r < 4; r++) {
    float M = fmaxf(redmx[0][q4 * 4 + r], redmx[1][q4 * 4 + r]);
    float acc = 0.f;
#pragma unroll
    for (int kt = 0; kt < 4; kt++) {
      float e = __expf((s[kt][r] - M) * scale);
      s[kt][r] = e;
      acc += e;
    }
#pragma unroll
    for (int msk = 1; msk < 16; msk <<= 1) acc += __shfl_xor(acc, msk);
    if (m16 == 0) redsm[w][q4 * 4 + r] = acc;
  }
#pragma unroll
  for (int kt = 0; kt < 4; kt++)
#pragma unroll
    for (int r = 0; r < 4; r++)
      P[q4 * 4 + r][w * 64 + kt * 16 + m16] = f2bf(s[kt][r]);
  __syncthreads();
  if (tid < 16) invd[tid] = 1.0f / (redsm[0][tid] + redsm[1][tid]);
  __syncthreads();

  short8 pf[4];
#pragma unroll
  for (int kc = 0; kc < 4; kc++)
    pf[kc] = *(const short8*)(&P[m16][kc * 32 + q4 * 8]);
  f32x4 o[4];
#pragma unroll
  for (int dt = 0; dt < 4; dt++)
#pragma unroll
    for (int r = 0; r < 4; r++) o[dt][r] = 0.f;
#pragma unroll
  for (int dt = 0; dt < 4; dt++) {
    int dhl = (w * 4 + dt) * 16 + m16;
#pragma unroll
    for (int kc = 0; kc < 4; kc++) {
      short8 vf = *(const short8*)(Vtile + (size_t)dhl * 128 + kc * 32 + q4 * 8);
      o[dt] = __builtin_amdgcn_mfma_f32_16x16x32_bf16(pf[kc], vf, o[dt], 0, 0, 0);
    }
  }
#pragma unroll
  for (int dt = 0; dt < 4; dt++)
#pragma unroll
    for (int r = 0; r < 4; r++) {
      int row = q4 * 4 + r;
      float val = o[dt][r] * invd[row];
      Ob[(size_t)(b * 16 + row) * D + h * 128 + (w * 4 + dt) * 16 + m16] = f2bf(val);
    }
}

// ============ kernel 4: Wpart[z] = O @ Wo[z-slice]  (split-K=8, plain stores) ============
__global__ __launch_bounds__(256, 3) void gemm_wo(const u16* __restrict__ Ob,
                                                  const u16* __restrict__ WoT,
                                                  float* __restrict__ Wpart) {
  __shared__ u16 smem[2 * 128 * 64];   // 32 KB
  u16* As = smem;
  u16* Bs = smem + 8192;
  int m0 = blockIdx.x * 128, n0 = blockIdx.y * 128;
  int z = blockIdx.z;
  int k0 = z * 256;
  f32x4 acc[4][4];
#pragma unroll
  for (int i = 0; i < 4; i++)
#pragma unroll
    for (int j = 0; j < 4; j++)
#pragma unroll
      for (int r = 0; r < 4; r++) acc[i][j][r] = 0.f;
  gemm_tile(Ob, WoT, false, m0, n0, k0, k0 + 256, As, Bs, acc);
  float* C = Wpart + (size_t)z * 256 * D;
  int tid = threadIdx.x, wid = tid >> 6, lane = tid & 63;
  int q4 = lane >> 4, m16 = lane & 15;
  int wm = wid >> 1, wn = wid & 1;
#pragma unroll
  for (int i = 0; i < 4; i++)
#pragma unroll
    for (int j = 0; j < 4; j++)
#pragma unroll
      for (int r = 0; r < 4; r++) {
        int row = m0 + wm * 64 + i * 16 + q4 * 4 + r;
        int col = n0 + wn * 64 + j * 16 + m16;
        C[(size_t)row * D + col] = acc[i][j][r];
      }
}

// ============ kernel 5: out[0:256] += sum_z Wpart[z]  (vectorized, no atomics) ============
__global__ __launch_bounds__(256) void reduce_wo(const float* __restrict__ Wpart,
                                                 float* __restrict__ out) {
  int i = (blockIdx.x * 256 + threadIdx.x) * 4;   // 512 blocks cover 256*2048 elems
  float4 s = *(const float4*)(out + i);           // residual base (out = x)
#pragma unroll
  for (int z = 0; z < 8; z++) {
    float4 p = *(const float4*)(Wpart + (size_t)z * 256 * D + i);
    s.x += p.x; s.y += p.y; s.z += p.z; s.w += p.w;
  }
  *(float4*)(out + i) = s;
}

extern "C" void kernel_launch(void* const* d_in, const int* in_sizes, int n_in,
                              void* d_out, int out_size, void* d_ws, size_t ws_size,
                              hipStream_t stream) {
  const float* x  = (const float*)d_in[0];
  const float* Wq = (const float*)d_in[1];
  const float* Wk = (const float*)d_in[2];
  const float* Wv = (const float*)d_in[3];
  const float* Wo = (const float*)d_in[4];
  float* out = (float*)d_out;
  char* w = (char*)d_ws;
  const size_t MB = 1u << 20;
  u16*   xn    = (u16*)(w);              // 0-8
  u16*   WqT   = (u16*)(w + 8 * MB);     // 8-16
  u16*   WkT   = (u16*)(w + 16 * MB);    // 16-24
  u16*   WvT   = (u16*)(w + 24 * MB);    // 24-32
  u16*   WoT   = (u16*)(w + 32 * MB);    // 32-40
  u16*   K3    = (u16*)(w + 40 * MB);    // 40-48
  u16*   V3    = (u16*)(w + 48 * MB);    // 48-56
  u16*   Q3    = (u16*)(w + 56 * MB);    // 56-57
  u16*   Obf   = (u16*)(w + 57 * MB);    // 57-58
  float* Wpart = (float*)(w + 58 * MB);  // 58-74  (8 x 2MB fp32 partials)

  prep<<<dim3(6144), dim3(256), 0, stream>>>(x, Wq, Wk, Wv, Wo, xn, out, WqT, WkT, WvT, WoT);
  gemm_mega<<<dim3(544), dim3(256), 0, stream>>>(xn, WkT, WqT, WvT, K3, Q3, V3);
  attn<<<dim3(256), dim3(128), 0, stream>>>(Q3, K3, V3, Obf);
  gemm_wo<<<dim3(2, 16, 8), dim3(256), 0, stream>>>(Obf, WoT, Wpart);
  reduce_wo<<<dim3(512), dim3(256), 0, stream>>>(Wpart, out);
}